// Round 1
// baseline (1198.361 us; speedup 1.0000x reference)
//
#include <hip/hip_runtime.h>
#include <math.h>

#define DM   1024
#define TTOK 2048
#define NTOK 4096   // B*T = 2*2048

// ---------- wave-subgroup reductions (row group = 16 consecutive lanes) ----------
__device__ __forceinline__ float rsum16(float v) {
    v += __shfl_xor(v, 1, 16);
    v += __shfl_xor(v, 2, 16);
    v += __shfl_xor(v, 4, 16);
    v += __shfl_xor(v, 8, 16);
    return v;
}
__device__ __forceinline__ float rmax16(float v) {
    v = fmaxf(v, __shfl_xor(v, 1, 16));
    v = fmaxf(v, __shfl_xor(v, 2, 16));
    v = fmaxf(v, __shfl_xor(v, 4, 16));
    v = fmaxf(v, __shfl_xor(v, 8, 16));
    return v;
}

// =====================================================================
// GEMM: C[m,n] = sum_k A[m,k] * W[n,k]   (A: 4096x1024, W: 1024x1024)
// MODE 0: grid.z selects (Wa,Da)/(Wb,Db)/(Wc,Dc); store into (B,H,T,64)
// MODE 1: single W; store row-major (B*T, 1024)
// 128x128 tile, BK=16, 256 threads, 8x8 micro-tile.
// =====================================================================
template<int MODE>
__global__ __launch_bounds__(256)
void gemm_xwt(const float* __restrict__ A,
              const float* __restrict__ Wa,
              const float* __restrict__ Wb,
              const float* __restrict__ Wc,
              float* __restrict__ Da,
              float* __restrict__ Db,
              float* __restrict__ Dc)
{
    const float* W; float* D;
    if (MODE == 0) {
        int z = blockIdx.z;
        W = (z == 0) ? Wa : (z == 1) ? Wb : Wc;
        D = (z == 0) ? Da : (z == 1) ? Db : Dc;
    } else { W = Wa; D = Da; }

    __shared__ float As[16][128];   // [k][m]
    __shared__ float Bs[16][128];   // [k][n]

    const int tid = threadIdx.x;
    const int tx  = tid & 15;       // n micro-block
    const int ty  = tid >> 4;       // m micro-block
    const int m0  = blockIdx.y * 128;
    const int n0  = blockIdx.x * 128;

    const int srow = tid >> 1;          // 0..127
    const int scol = (tid & 1) << 3;    // 0 or 8

    float acc[8][8];
#pragma unroll
    for (int i = 0; i < 8; ++i)
#pragma unroll
        for (int j = 0; j < 8; ++j) acc[i][j] = 0.0f;

    const float* arow = A + (size_t)(m0 + srow) * DM + scol;
    const float* wrow = W + (size_t)(n0 + srow) * DM + scol;

    for (int k0 = 0; k0 < DM; k0 += 16) {
        float4 a0 = *(const float4*)(arow + k0);
        float4 a1 = *(const float4*)(arow + k0 + 4);
        float4 b0 = *(const float4*)(wrow + k0);
        float4 b1 = *(const float4*)(wrow + k0 + 4);
        __syncthreads();   // previous tile's compute reads done
        As[scol + 0][srow] = a0.x; As[scol + 1][srow] = a0.y;
        As[scol + 2][srow] = a0.z; As[scol + 3][srow] = a0.w;
        As[scol + 4][srow] = a1.x; As[scol + 5][srow] = a1.y;
        As[scol + 6][srow] = a1.z; As[scol + 7][srow] = a1.w;
        Bs[scol + 0][srow] = b0.x; Bs[scol + 1][srow] = b0.y;
        Bs[scol + 2][srow] = b0.z; Bs[scol + 3][srow] = b0.w;
        Bs[scol + 4][srow] = b1.x; Bs[scol + 5][srow] = b1.y;
        Bs[scol + 6][srow] = b1.z; Bs[scol + 7][srow] = b1.w;
        __syncthreads();
#pragma unroll
        for (int k = 0; k < 16; ++k) {
            float4 aA = *(const float4*)&As[k][ty * 8];
            float4 aB = *(const float4*)&As[k][ty * 8 + 4];
            float4 bA = *(const float4*)&Bs[k][tx * 8];
            float4 bB = *(const float4*)&Bs[k][tx * 8 + 4];
            float a[8] = {aA.x, aA.y, aA.z, aA.w, aB.x, aB.y, aB.z, aB.w};
            float b[8] = {bA.x, bA.y, bA.z, bA.w, bB.x, bB.y, bB.z, bB.w};
#pragma unroll
            for (int i = 0; i < 8; ++i)
#pragma unroll
                for (int j = 0; j < 8; ++j)
                    acc[i][j] = fmaf(a[i], b[j], acc[i][j]);
        }
    }

    if (MODE == 1) {
#pragma unroll
        for (int i = 0; i < 8; ++i) {
            int m = m0 + ty * 8 + i;
            float* dp = D + (size_t)m * DM + n0 + tx * 8;
            *(float4*)(dp)     = make_float4(acc[i][0], acc[i][1], acc[i][2], acc[i][3]);
            *(float4*)(dp + 4) = make_float4(acc[i][4], acc[i][5], acc[i][6], acc[i][7]);
        }
    } else {
        // (m,n) -> Q[b, h, t, d] : b=m/2048, t=m%2048, h=n/64, d=n%64
#pragma unroll
        for (int i = 0; i < 8; ++i) {
            int m = m0 + ty * 8 + i;
            int b = m >> 11, t = m & 2047;
#pragma unroll
            for (int j4 = 0; j4 < 2; ++j4) {
                int n = n0 + tx * 8 + j4 * 4;
                int h = n >> 6, d = n & 63;
                float* dp = D + ((((size_t)b * 16 + h) * TTOK + t) * 64 + d);
                *(float4*)dp = make_float4(acc[i][j4 * 4 + 0], acc[i][j4 * 4 + 1],
                                           acc[i][j4 * 4 + 2], acc[i][j4 * 4 + 3]);
            }
        }
    }
}

// =====================================================================
// Flash-style attention + exclusive-output-mod epilogue.
// One block: one (b,h), 64 query rows. 128 threads (ty=0..7 rows*8, tx=0..15 cols*4).
// Online softmax over 32 key-tiles of 64. P goes through LDS (Pt unions Kt).
// Epilogue: Y=O/l ; Z = Y - (Y.V/max(V.V,tiny)) V ; cleanup per reference; store merged heads.
// =====================================================================
__global__ __launch_bounds__(128)
void attn_fp32(const float* __restrict__ Qg,
               const float* __restrict__ Kg,
               const float* __restrict__ Vg,
               float* __restrict__ Zm)
{
    const int bh = blockIdx.y;            // b*16 + h
    const int q0 = blockIdx.x * 64;
    const float* Qp = Qg + (size_t)bh * TTOK * 64;
    const float* Kp = Kg + (size_t)bh * TTOK * 64;
    const float* Vp = Vg + (size_t)bh * TTOK * 64;

    __shared__ float Qt[64][64];       // [d][r], Q pre-scaled by 1/8
    __shared__ float KPu[64 * 68];     // union: Kt [d][c] stride 64  /  Pt [c][r] stride 68
    __shared__ float Vs[64][68];       // [c][d]

    float* Kt = KPu;
    float* Pt = KPu;

    const int tid = threadIdx.x;       // 0..127
    const int tx  = tid & 15;
    const int ty  = tid >> 4;          // 0..7

    // ---- stage Q transposed, fold sm_scale = 0.125 ----
    {
        int r = tid >> 1;
        const float* qrow = Qp + (size_t)(q0 + r) * 64;
#pragma unroll
        for (int i = 0; i < 8; ++i) {
            int d = ((tid & 1) * 8 + i) * 4;
            float4 v = *(const float4*)(qrow + d);
            Qt[d + 0][r] = v.x * 0.125f;
            Qt[d + 1][r] = v.y * 0.125f;
            Qt[d + 2][r] = v.z * 0.125f;
            Qt[d + 3][r] = v.w * 0.125f;
        }
    }

    float O[8][4];
    float m_[8], l_[8];
#pragma unroll
    for (int i = 0; i < 8; ++i) {
        m_[i] = -INFINITY; l_[i] = 0.0f;
#pragma unroll
        for (int j = 0; j < 4; ++j) O[i][j] = 0.0f;
    }

    for (int kb = 0; kb < TTOK / 64; ++kb) {
        // ---- stage K (transposed) and V (natural) ----
        const int r = tid >> 1;
        const float* krow = Kp + ((size_t)(kb * 64 + r)) * 64;
        const float* vrow = Vp + ((size_t)(kb * 64 + r)) * 64;
        float4 kv[8], vv[8];
#pragma unroll
        for (int i = 0; i < 8; ++i) {
            int d = ((tid & 1) * 8 + i) * 4;
            kv[i] = *(const float4*)(krow + d);
            vv[i] = *(const float4*)(vrow + d);
        }
        __syncthreads();   // prev tile PV reads (Pt, Vs) done
#pragma unroll
        for (int i = 0; i < 8; ++i) {
            int d = ((tid & 1) * 8 + i) * 4;
            Kt[(d + 0) * 64 + r] = kv[i].x;
            Kt[(d + 1) * 64 + r] = kv[i].y;
            Kt[(d + 2) * 64 + r] = kv[i].z;
            Kt[(d + 3) * 64 + r] = kv[i].w;
            *(float4*)&Vs[r][d] = vv[i];
        }
        __syncthreads();

        // ---- S micro-tile: rows ty*8.., cols tx*4.. ----
        float s[8][4];
#pragma unroll
        for (int i = 0; i < 8; ++i)
#pragma unroll
            for (int j = 0; j < 4; ++j) s[i][j] = 0.0f;

#pragma unroll 8
        for (int d = 0; d < 64; ++d) {
            float4 aA = *(const float4*)&Qt[d][ty * 8];
            float4 aB = *(const float4*)&Qt[d][ty * 8 + 4];
            float4 bA = *(const float4*)&Kt[d * 64 + tx * 4];
            float a[8] = {aA.x, aA.y, aA.z, aA.w, aB.x, aB.y, aB.z, aB.w};
            float b[4] = {bA.x, bA.y, bA.z, bA.w};
#pragma unroll
            for (int i = 0; i < 8; ++i)
#pragma unroll
                for (int j = 0; j < 4; ++j)
                    s[i][j] = fmaf(a[i], b[j], s[i][j]);
        }

        // ---- online softmax (row reductions across the 16-lane group) ----
#pragma unroll
        for (int i = 0; i < 8; ++i) {
            float tm = fmaxf(fmaxf(s[i][0], s[i][1]), fmaxf(s[i][2], s[i][3]));
            tm = rmax16(tm);
            float mnew  = fmaxf(m_[i], tm);
            float alpha = __expf(m_[i] - mnew);
            float p0 = __expf(s[i][0] - mnew);
            float p1 = __expf(s[i][1] - mnew);
            float p2 = __expf(s[i][2] - mnew);
            float p3 = __expf(s[i][3] - mnew);
            float ts = rsum16((p0 + p1) + (p2 + p3));
            l_[i] = l_[i] * alpha + ts;
            m_[i] = mnew;
            O[i][0] *= alpha; O[i][1] *= alpha; O[i][2] *= alpha; O[i][3] *= alpha;
            s[i][0] = p0; s[i][1] = p1; s[i][2] = p2; s[i][3] = p3;
        }

        __syncthreads();   // all Kt reads done; safe to overwrite with Pt
#pragma unroll
        for (int cc = 0; cc < 4; ++cc) {
            int c = tx * 4 + cc;
            *(float4*)&Pt[c * 68 + ty * 8] =
                make_float4(s[0][cc], s[1][cc], s[2][cc], s[3][cc]);
            *(float4*)&Pt[c * 68 + ty * 8 + 4] =
                make_float4(s[4][cc], s[5][cc], s[6][cc], s[7][cc]);
        }
        __syncthreads();

        // ---- PV: O[i][j] += sum_c P[r][c] * V[c][d] ----
#pragma unroll 8
        for (int c = 0; c < 64; ++c) {
            float4 pA = *(const float4*)&Pt[c * 68 + ty * 8];
            float4 pB = *(const float4*)&Pt[c * 68 + ty * 8 + 4];
            float4 vB = *(const float4*)&Vs[c][tx * 4];
            float pa[8] = {pA.x, pA.y, pA.z, pA.w, pB.x, pB.y, pB.z, pB.w};
            float vb[4] = {vB.x, vB.y, vB.z, vB.w};
#pragma unroll
            for (int i = 0; i < 8; ++i)
#pragma unroll
                for (int j = 0; j < 4; ++j)
                    O[i][j] = fmaf(pa[i], vb[j], O[i][j]);
        }
    }

    // ---- epilogue: Y = O/l ; exclusive output mod ; store merged heads ----
    const int b = bh >> 4, h = bh & 15;
#pragma unroll
    for (int i = 0; i < 8; ++i) {
        int q = q0 + ty * 8 + i;
        float inv = 1.0f / l_[i];
        float y[4];
#pragma unroll
        for (int j = 0; j < 4; ++j) y[j] = O[i][j] * inv;
        float4 v4 = *(const float4*)(Vp + (size_t)q * 64 + tx * 4);
        float vq[4] = {v4.x, v4.y, v4.z, v4.w};
        float yv = 0.f, vv2 = 0.f, yy = 0.f;
#pragma unroll
        for (int j = 0; j < 4; ++j) {
            yv  += y[j] * vq[j];
            vv2 += vq[j] * vq[j];
            yy  += y[j] * y[j];
        }
        yv = rsum16(yv); vv2 = rsum16(vv2); yy = rsum16(yy);
        float scl = (vv2 > 0.0f) ? yv / fmaxf(vv2, 1.1754943508222875e-38f) : 0.0f;
        float z[4]; float zz = 0.f;
#pragma unroll
        for (int j = 0; j < 4; ++j) { z[j] = y[j] - scl * vq[j]; zz += z[j] * z[j]; }
        zz = rsum16(zz);
        float znorm = sqrtf(zz);
        float refn  = fmaxf(sqrtf(yy), sqrtf(vv2));
        float tol   = 1.1920928955078125e-07f * 64.0f * refn;
        if (vv2 > 0.0f && znorm <= tol) { z[0] = z[1] = z[2] = z[3] = 0.0f; }
        float* dst = Zm + (((size_t)b * TTOK + q) * DM) + h * 64 + tx * 4;
        *(float4*)dst = make_float4(z[0], z[1], z[2], z[3]);
    }
}

// =====================================================================
extern "C" void kernel_launch(void* const* d_in, const int* in_sizes, int n_in,
                              void* d_out, int out_size, void* d_ws, size_t ws_size,
                              hipStream_t stream) {
    const float* x  = (const float*)d_in[0];
    const float* Wq = (const float*)d_in[1];
    const float* Wk = (const float*)d_in[2];
    const float* Wv = (const float*)d_in[3];
    const float* Wo = (const float*)d_in[4];
    float* out = (float*)d_out;

    const size_t C = (size_t)NTOK * DM;      // 4M floats
    float* Q  = (float*)d_ws;
    float* K  = Q + C;
    float* V  = K + C;
    float* Zm = V + C;                        // 64 MB total

    // QKV projections, stored directly in (B,H,T,64)
    gemm_xwt<0><<<dim3(DM / 128, NTOK / 128, 3), 256, 0, stream>>>(
        x, Wq, Wk, Wv, Q, K, V);

    // attention + exclusive output mod -> Zm (B,T,D merged heads)
    attn_fp32<<<dim3(TTOK / 64, 32), 128, 0, stream>>>(Q, K, V, Zm);

    // out = Zm @ Wo^T
    gemm_xwt<1><<<dim3(DM / 128, NTOK / 128, 1), 256, 0, stream>>>(
        Zm, Wo, Wo, Wo, out, out, out);
}

// Round 2
// 273.906 us; speedup vs baseline: 4.3751x; 4.3751x over previous
//
#include <hip/hip_runtime.h>
#include <math.h>

#define DM   1024
#define TTOK 2048
#define NTOK 4096   // B*T

typedef __bf16 bf16x8 __attribute__((ext_vector_type(8)));
typedef float  f32x4  __attribute__((ext_vector_type(4)));

#define GLDS16(g, l) __builtin_amdgcn_global_load_lds( \
    (__attribute__((address_space(1))) void*)(g),      \
    (__attribute__((address_space(3))) void*)(l), 16, 0, 0)

__device__ __forceinline__ float rsum16(float v) {
    v += __shfl_xor(v, 1, 16);
    v += __shfl_xor(v, 2, 16);
    v += __shfl_xor(v, 4, 16);
    v += __shfl_xor(v, 8, 16);
    return v;
}
__device__ __forceinline__ float rmax16(float v) {
    v = fmaxf(v, __shfl_xor(v, 1, 16));
    v = fmaxf(v, __shfl_xor(v, 2, 16));
    v = fmaxf(v, __shfl_xor(v, 4, 16));
    v = fmaxf(v, __shfl_xor(v, 8, 16));
    return v;
}

// ---------------- fp32 -> bf16 convert ----------------
__global__ __launch_bounds__(256)
void cvt_bf16(const float* __restrict__ s, __bf16* __restrict__ d, int n) {
    int i = (blockIdx.x * 256 + threadIdx.x) * 8;
    if (i >= n) return;
    float4 a = *(const float4*)(s + i);
    float4 b = *(const float4*)(s + i + 4);
    bf16x8 v;
    v[0] = (__bf16)a.x; v[1] = (__bf16)a.y; v[2] = (__bf16)a.z; v[3] = (__bf16)a.w;
    v[4] = (__bf16)b.x; v[5] = (__bf16)b.y; v[6] = (__bf16)b.z; v[7] = (__bf16)b.w;
    *(bf16x8*)(d + i) = v;
}

// =====================================================================
// bf16 MFMA GEMM: C[m,n] = sum_k A[m,k] * W[n,k]  (W row-major = B^T)
// 128x128 tile, BK=32, 256 threads (4 waves, 2x2), 16x16x32 MFMA,
// global_load_lds width-16 staging (m97 structure).
// MODE 0: z selects Wq/Wk/Wv; epilogue -> (B,H,T,64) bf16 (z0 scaled 1/8;
//         z2 writes natural AND transposed V).
// MODE 1: fp32 row-major output.
// =====================================================================
template<int MODE>
__global__ __launch_bounds__(256)
void gemm_bf16(const __bf16* __restrict__ A,
               const __bf16* __restrict__ W0, const __bf16* __restrict__ W1,
               const __bf16* __restrict__ W2,
               __bf16* __restrict__ Oq, __bf16* __restrict__ Ok,
               __bf16* __restrict__ Ovn, __bf16* __restrict__ Ovt,
               float* __restrict__ Of)
{
    const int z = (MODE == 0) ? blockIdx.z : 0;
    const __bf16* W = (z == 0) ? W0 : (z == 1) ? W1 : W2;

    __shared__ __attribute__((aligned(16))) __bf16 As[128 * 32];
    __shared__ __attribute__((aligned(16))) __bf16 Bs[128 * 32];

    const int tid  = threadIdx.x;
    const int lane = tid & 63;
    const int wave = tid >> 6;
    const int wm = wave & 1, wn = wave >> 1;
    const int col = lane & 15, quad = lane >> 4;
    const int m0 = blockIdx.y * 128, n0 = blockIdx.x * 128;

    const __bf16* Ag = A + (size_t)(m0 + (tid >> 2)) * DM + (tid & 3) * 8;
    const __bf16* Wg = W + (size_t)(n0 + (tid >> 2)) * DM + (tid & 3) * 8;
    __bf16* lA = As + tid * 8;
    __bf16* lB = Bs + tid * 8;

    f32x4 acc[4][4];
#pragma unroll
    for (int i = 0; i < 4; ++i)
#pragma unroll
        for (int j = 0; j < 4; ++j)
#pragma unroll
            for (int r = 0; r < 4; ++r) acc[i][j][r] = 0.0f;

    for (int k0 = 0; k0 < DM; k0 += 32) {
        __syncthreads();
        GLDS16(Ag + k0,                      lA);
        GLDS16(Ag + (size_t)64 * DM + k0,    lA + 2048);
        GLDS16(Wg + k0,                      lB);
        GLDS16(Wg + (size_t)64 * DM + k0,    lB + 2048);
        __syncthreads();
        bf16x8 af[4], bfr[4];
#pragma unroll
        for (int i = 0; i < 4; ++i)
            af[i] = *(const bf16x8*)&As[(wm * 64 + i * 16 + col) * 32 + quad * 8];
#pragma unroll
        for (int j = 0; j < 4; ++j)
            bfr[j] = *(const bf16x8*)&Bs[(wn * 64 + j * 16 + col) * 32 + quad * 8];
#pragma unroll
        for (int i = 0; i < 4; ++i)
#pragma unroll
            for (int j = 0; j < 4; ++j)
                acc[i][j] = __builtin_amdgcn_mfma_f32_16x16x32_bf16(af[i], bfr[j], acc[i][j], 0, 0, 0);
    }

#pragma unroll
    for (int i = 0; i < 4; ++i) {
#pragma unroll
        for (int j = 0; j < 4; ++j) {
#pragma unroll
            for (int r = 0; r < 4; ++r) {
                int m = m0 + wm * 64 + i * 16 + quad * 4 + r;
                int n = n0 + wn * 64 + j * 16 + col;
                float v = acc[i][j][r];
                if (MODE == 1) {
                    Of[(size_t)m * DM + n] = v;
                } else {
                    int b = m >> 11, t = m & 2047;
                    int h = n >> 6,  d = n & 63;
                    size_t bhtd = (((size_t)(b * 16 + h)) * TTOK + t) * 64 + d;
                    if (z == 0)      Oq[bhtd] = (__bf16)(v * 0.125f);
                    else if (z == 1) Ok[bhtd] = (__bf16)v;
                    else {
                        Ovn[bhtd] = (__bf16)v;
                        Ovt[(((size_t)(b * 16 + h)) * 64 + d) * TTOK + t] = (__bf16)v;
                    }
                }
            }
        }
    }
}

// =====================================================================
// MFMA flash attention + exclusive-output-mod epilogue.
// Block: 256 threads (4 waves), 64 q-rows; wave w owns q-rows [16w,16w+16).
// K/Vt/Q/P tiles in LDS padded to stride 72 (bank-balanced b128 frags).
// Online softmax in C-layout (row = quad*4+reg matches per-reg m/l).
// =====================================================================
__global__ __launch_bounds__(256)
void attn_mfma(const __bf16* __restrict__ Qg, const __bf16* __restrict__ Kg,
               const __bf16* __restrict__ Vtg, const __bf16* __restrict__ Vng,
               __bf16* __restrict__ Zm)
{
    const int bh = blockIdx.y;
    const int q0 = blockIdx.x * 64;
    const size_t base = (size_t)bh * TTOK * 64;

    __shared__ __attribute__((aligned(16))) __bf16 Qs[64 * 72];
    __shared__ __attribute__((aligned(16))) __bf16 Ks[64 * 72];
    __shared__ __attribute__((aligned(16))) __bf16 Vs[64 * 72];   // [d][key]
    __shared__ __attribute__((aligned(16))) __bf16 Ps[64 * 72];   // [q][key]

    const int tid  = threadIdx.x;
    const int lane = tid & 63, wave = tid >> 6;
    const int col  = lane & 15, quad = lane >> 4;

    // stage Q (already pre-scaled by 1/8 in the QKV GEMM)
#pragma unroll
    for (int i = 0; i < 2; ++i) {
        int c = tid + 256 * i;
        int r = c >> 3, off = (c & 7) * 8;
        *(bf16x8*)&Qs[r * 72 + off] =
            *(const bf16x8*)(Qg + base + (size_t)(q0 + r) * 64 + off);
    }

    f32x4 O[4];
    float m_[4], l_[4];
#pragma unroll
    for (int r = 0; r < 4; ++r) {
        m_[r] = -INFINITY; l_[r] = 0.0f;
#pragma unroll
        for (int n = 0; n < 4; ++n) O[n][r] = 0.0f;
    }

    for (int kb = 0; kb < TTOK / 64; ++kb) {
        bf16x8 kreg[2], vreg[2];
#pragma unroll
        for (int i = 0; i < 2; ++i) {
            int c = tid + 256 * i;
            int r = c >> 3, off = (c & 7) * 8;
            kreg[i] = *(const bf16x8*)(Kg + base + (size_t)(kb * 64 + r) * 64 + off);
            vreg[i] = *(const bf16x8*)(Vtg + base + (size_t)r * TTOK + kb * 64 + off);
        }
        __syncthreads();   // prior tile's Ks/Vs reads complete
#pragma unroll
        for (int i = 0; i < 2; ++i) {
            int c = tid + 256 * i;
            int r = c >> 3, off = (c & 7) * 8;
            *(bf16x8*)&Ks[r * 72 + off] = kreg[i];
            *(bf16x8*)&Vs[r * 72 + off] = vreg[i];
        }
        __syncthreads();

        // ---- S = Q K^T (16 q-rows x 64 keys per wave) ----
        const int qrow = (wave * 16 + col) * 72;
        bf16x8 aq0 = *(const bf16x8*)&Qs[qrow + quad * 8];
        bf16x8 aq1 = *(const bf16x8*)&Qs[qrow + 32 + quad * 8];
        f32x4 s[4];
#pragma unroll
        for (int n = 0; n < 4; ++n) {
#pragma unroll
            for (int r = 0; r < 4; ++r) s[n][r] = 0.0f;
            bf16x8 b0 = *(const bf16x8*)&Ks[(n * 16 + col) * 72 + quad * 8];
            bf16x8 b1 = *(const bf16x8*)&Ks[(n * 16 + col) * 72 + 32 + quad * 8];
            s[n] = __builtin_amdgcn_mfma_f32_16x16x32_bf16(aq0, b0, s[n], 0, 0, 0);
            s[n] = __builtin_amdgcn_mfma_f32_16x16x32_bf16(aq1, b1, s[n], 0, 0, 0);
        }

        // ---- online softmax; write P (bf16) to own wave's Ps rows ----
#pragma unroll
        for (int r = 0; r < 4; ++r) {
            float gm = fmaxf(fmaxf(s[0][r], s[1][r]), fmaxf(s[2][r], s[3][r]));
            gm = rmax16(gm);
            float mnew  = fmaxf(m_[r], gm);
            float alpha = __expf(m_[r] - mnew);
            float p0 = __expf(s[0][r] - mnew), p1 = __expf(s[1][r] - mnew);
            float p2 = __expf(s[2][r] - mnew), p3 = __expf(s[3][r] - mnew);
            float ps = rsum16((p0 + p1) + (p2 + p3));
            l_[r] = l_[r] * alpha + ps; m_[r] = mnew;
            O[0][r] *= alpha; O[1][r] *= alpha; O[2][r] *= alpha; O[3][r] *= alpha;
            int pr = (wave * 16 + quad * 4 + r) * 72 + col;
            Ps[pr +  0] = (__bf16)p0;
            Ps[pr + 16] = (__bf16)p1;
            Ps[pr + 32] = (__bf16)p2;
            Ps[pr + 48] = (__bf16)p3;
        }

        // ---- O += P V  (Ps rows are intra-wave: no barrier needed) ----
#pragma unroll
        for (int ks = 0; ks < 2; ++ks) {
            bf16x8 ap = *(const bf16x8*)&Ps[(wave * 16 + col) * 72 + ks * 32 + quad * 8];
#pragma unroll
            for (int n = 0; n < 4; ++n) {
                bf16x8 bv = *(const bf16x8*)&Vs[(n * 16 + col) * 72 + ks * 32 + quad * 8];
                O[n] = __builtin_amdgcn_mfma_f32_16x16x32_bf16(ap, bv, O[n], 0, 0, 0);
            }
        }
    }

    // ---- epilogue: Y = O/l ; exclusive output mod ; merged-head bf16 store ----
    const int b = bh >> 4, h = bh & 15;
#pragma unroll
    for (int r = 0; r < 4; ++r) {
        int q = q0 + wave * 16 + quad * 4 + r;
        float inv = 1.0f / l_[r];
        float y[4], vq[4];
        float yv = 0.f, vv2 = 0.f, yy = 0.f;
#pragma unroll
        for (int n = 0; n < 4; ++n) {
            y[n]  = O[n][r] * inv;
            vq[n] = (float)Vng[base + (size_t)q * 64 + n * 16 + col];
            yv  += y[n] * vq[n];
            vv2 += vq[n] * vq[n];
            yy  += y[n] * y[n];
        }
        yv = rsum16(yv); vv2 = rsum16(vv2); yy = rsum16(yy);
        float scl = (vv2 > 0.0f) ? yv / fmaxf(vv2, 1.1754943508222875e-38f) : 0.0f;
        float zv[4]; float zz = 0.f;
#pragma unroll
        for (int n = 0; n < 4; ++n) { zv[n] = y[n] - scl * vq[n]; zz += zv[n] * zv[n]; }
        zz = rsum16(zz);
        float znorm = sqrtf(zz);
        float refn  = fmaxf(sqrtf(yy), sqrtf(vv2));
        bool  wipe  = (vv2 > 0.0f) && (znorm <= 1.1920928955078125e-07f * 64.0f * refn);
#pragma unroll
        for (int n = 0; n < 4; ++n)
            Zm[((size_t)(b * TTOK + q)) * DM + h * 64 + n * 16 + col] =
                (__bf16)(wipe ? 0.0f : zv[n]);
    }
}

// =====================================================================
extern "C" void kernel_launch(void* const* d_in, const int* in_sizes, int n_in,
                              void* d_out, int out_size, void* d_ws, size_t ws_size,
                              hipStream_t stream) {
    const float* x  = (const float*)d_in[0];
    const float* Wq = (const float*)d_in[1];
    const float* Wk = (const float*)d_in[2];
    const float* Wv = (const float*)d_in[3];
    const float* Wo = (const float*)d_in[4];

    const size_t NX = (size_t)NTOK * DM;   // 4M
    const size_t NW = (size_t)DM * DM;     // 1M
    __bf16* xb  = (__bf16*)d_ws;
    __bf16* wqb = xb  + NX;
    __bf16* wkb = wqb + NW;
    __bf16* wvb = wkb + NW;
    __bf16* wob = wvb + NW;
    __bf16* Qb  = wob + NW;
    __bf16* Kb  = Qb  + NX;
    __bf16* Vnb = Kb  + NX;
    __bf16* Vtb = Vnb + NX;
    __bf16* Zmb = Vtb + NX;   // total 28M bf16 = 56 MB

    cvt_bf16<<<NX / 2048, 256, 0, stream>>>(x,  xb,  (int)NX);
    cvt_bf16<<<NW / 2048, 256, 0, stream>>>(Wq, wqb, (int)NW);
    cvt_bf16<<<NW / 2048, 256, 0, stream>>>(Wk, wkb, (int)NW);
    cvt_bf16<<<NW / 2048, 256, 0, stream>>>(Wv, wvb, (int)NW);
    cvt_bf16<<<NW / 2048, 256, 0, stream>>>(Wo, wob, (int)NW);

    gemm_bf16<0><<<dim3(DM / 128, NTOK / 128, 3), 256, 0, stream>>>(
        xb, wqb, wkb, wvb, Qb, Kb, Vnb, Vtb, nullptr);

    attn_mfma<<<dim3(TTOK / 64, 32), 256, 0, stream>>>(Qb, Kb, Vtb, Vnb, Zmb);

    gemm_bf16<1><<<dim3(DM / 128, NTOK / 128, 1), 256, 0, stream>>>(
        Zmb, wob, wob, wob, nullptr, nullptr, nullptr, nullptr, (float*)d_out);
}

// Round 3
// 222.661 us; speedup vs baseline: 5.3820x; 1.2301x over previous
//
#include <hip/hip_runtime.h>
#include <math.h>

#define DM   1024
#define TTOK 2048
#define NTOK 4096   // B*T

typedef __bf16 bf16x8 __attribute__((ext_vector_type(8)));
typedef __bf16 bf16x4 __attribute__((ext_vector_type(4)));
typedef float  f32x4  __attribute__((ext_vector_type(4)));

// Q pre-scale: sm_scale (1/8) * log2(e)  -> allows p = exp2(s)
#define QSCALE 0.18033688011112042f

#define GLDS16(g, l) __builtin_amdgcn_global_load_lds( \
    (__attribute__((address_space(1))) void*)(g),      \
    (__attribute__((address_space(3))) void*)(l), 16, 0, 0)

// sum across the 4 quads (lanes ^16, ^32) — full 64-lane wave
__device__ __forceinline__ float qsum(float v) {
    v += __shfl_xor(v, 16, 64);
    v += __shfl_xor(v, 32, 64);
    return v;
}

// ---------------- fp32 -> bf16 convert ----------------
__global__ __launch_bounds__(256)
void cvt_bf16(const float* __restrict__ s, __bf16* __restrict__ d, int n) {
    int i = (blockIdx.x * 256 + threadIdx.x) * 8;
    if (i >= n) return;
    float4 a = *(const float4*)(s + i);
    float4 b = *(const float4*)(s + i + 4);
    bf16x8 v;
    v[0] = (__bf16)a.x; v[1] = (__bf16)a.y; v[2] = (__bf16)a.z; v[3] = (__bf16)a.w;
    v[4] = (__bf16)b.x; v[5] = (__bf16)b.y; v[6] = (__bf16)b.z; v[7] = (__bf16)b.w;
    *(bf16x8*)(d + i) = v;
}

// =====================================================================
// bf16 MFMA GEMM: C[m,n] = sum_k A[m,k] * W[n,k]
// MODE 0: z=0 -> Q[b,h,t,d] scaled by QSCALE; z=1 -> K[b,h,t,d];
//         z=2 -> Vt[b,h,d,t] (packed b64 stores along t)
// MODE 1: fp32 row-major output (out-projection)
// =====================================================================
template<int MODE>
__global__ __launch_bounds__(256)
void gemm_bf16(const __bf16* __restrict__ A,
               const __bf16* __restrict__ W0, const __bf16* __restrict__ W1,
               const __bf16* __restrict__ W2,
               __bf16* __restrict__ Oq, __bf16* __restrict__ Ok,
               __bf16* __restrict__ Ovt, float* __restrict__ Of)
{
    const int z = (MODE == 0) ? blockIdx.z : 0;
    const __bf16* W = (z == 0) ? W0 : (z == 1) ? W1 : W2;

    __shared__ __attribute__((aligned(16))) __bf16 As[128 * 32];
    __shared__ __attribute__((aligned(16))) __bf16 Bs[128 * 32];

    const int tid  = threadIdx.x;
    const int lane = tid & 63;
    const int wave = tid >> 6;
    const int wm = wave & 1, wn = wave >> 1;
    const int col = lane & 15, quad = lane >> 4;
    const int m0 = blockIdx.y * 128, n0 = blockIdx.x * 128;

    const __bf16* Ag = A + (size_t)(m0 + (tid >> 2)) * DM + (tid & 3) * 8;
    const __bf16* Wg = W + (size_t)(n0 + (tid >> 2)) * DM + (tid & 3) * 8;
    __bf16* lA = As + tid * 8;
    __bf16* lB = Bs + tid * 8;

    f32x4 acc[4][4];
#pragma unroll
    for (int i = 0; i < 4; ++i)
#pragma unroll
        for (int j = 0; j < 4; ++j)
#pragma unroll
            for (int r = 0; r < 4; ++r) acc[i][j][r] = 0.0f;

    for (int k0 = 0; k0 < DM; k0 += 32) {
        __syncthreads();
        GLDS16(Ag + k0,                   lA);
        GLDS16(Ag + (size_t)64 * DM + k0, lA + 2048);
        GLDS16(Wg + k0,                   lB);
        GLDS16(Wg + (size_t)64 * DM + k0, lB + 2048);
        __syncthreads();
        bf16x8 af[4], bfr[4];
#pragma unroll
        for (int i = 0; i < 4; ++i)
            af[i] = *(const bf16x8*)&As[(wm * 64 + i * 16 + col) * 32 + quad * 8];
#pragma unroll
        for (int j = 0; j < 4; ++j)
            bfr[j] = *(const bf16x8*)&Bs[(wn * 64 + j * 16 + col) * 32 + quad * 8];
#pragma unroll
        for (int i = 0; i < 4; ++i)
#pragma unroll
            for (int j = 0; j < 4; ++j)
                acc[i][j] = __builtin_amdgcn_mfma_f32_16x16x32_bf16(af[i], bfr[j], acc[i][j], 0, 0, 0);
    }

#pragma unroll
    for (int i = 0; i < 4; ++i) {
#pragma unroll
        for (int j = 0; j < 4; ++j) {
            const int mb = m0 + wm * 64 + i * 16 + quad * 4;   // multiple of 4, no b-crossing
            const int n  = n0 + wn * 64 + j * 16 + col;
            if (MODE == 1) {
#pragma unroll
                for (int r = 0; r < 4; ++r)
                    Of[(size_t)(mb + r) * DM + n] = acc[i][j][r];
            } else {
                const int b = mb >> 11, t = mb & 2047;
                const int h = n >> 6,  d = n & 63;
                if (z == 2) {
                    bf16x4 pk;
#pragma unroll
                    for (int r = 0; r < 4; ++r) pk[r] = (__bf16)acc[i][j][r];
                    *(bf16x4*)&Ovt[(((size_t)(b * 16 + h)) * 64 + d) * TTOK + t] = pk;
                } else {
                    __bf16* dst = ((z == 0) ? Oq : Ok) +
                                  ((((size_t)(b * 16 + h)) * TTOK + t) * 64 + d);
                    const float sc = (z == 0) ? QSCALE : 1.0f;
#pragma unroll
                    for (int r = 0; r < 4; ++r) dst[(size_t)r * 64] = (__bf16)(acc[i][j][r] * sc);
                }
            }
        }
    }
}

// =====================================================================
// MFMA flash attention (transposed S, no-max softmax) + exclusive-mod.
// Block: 256 thr (4 waves), 128 q-rows; wave w owns q in [32w, 32w+32).
// S^T = K·Q^T  (C rows = keys -> contiguous-key P, b64 P writes)
// O^T = V^T·P^T (C rows = d, cols = q -> per-q l state is per-lane)
// p = exp2(s) with log2e folded into Q; l accumulated per-lane, reduced once.
// LDS: Ks/Vs 9KB each + QPs 18KB (Q staging, reused as P^T after hoist).
// =====================================================================
__global__ __launch_bounds__(256)
void attn_mfma(const __bf16* __restrict__ Qg, const __bf16* __restrict__ Kg,
               const __bf16* __restrict__ Vtg, __bf16* __restrict__ Zm)
{
    const int bh = blockIdx.y;
    const int q0 = blockIdx.x * 128;
    const size_t base = (size_t)bh * TTOK * 64;

    __shared__ __attribute__((aligned(16))) __bf16 Ks[64 * 72];
    __shared__ __attribute__((aligned(16))) __bf16 Vs[64 * 72];     // [d][key]
    __shared__ __attribute__((aligned(16))) __bf16 QPs[128 * 72];   // Q stage -> P^T [q][key]

    const int tid  = threadIdx.x;
    const int lane = tid & 63, wave = tid >> 6;
    const int col  = lane & 15, quad = lane >> 4;

    // ---- stage Q (pre-scaled by QSCALE in GEMM), then hoist frags ----
#pragma unroll
    for (int it = 0; it < 4; ++it) {
        int c = tid + 256 * it;
        int r = c >> 3, off = (c & 7) * 8;
        *(bf16x8*)&QPs[r * 72 + off] =
            *(const bf16x8*)(Qg + base + (size_t)(q0 + r) * 64 + off);
    }
    __syncthreads();
    bf16x8 qf[2][2];
#pragma unroll
    for (int nq = 0; nq < 2; ++nq)
#pragma unroll
        for (int ks = 0; ks < 2; ++ks)
            qf[nq][ks] = *(const bf16x8*)&QPs[(wave * 32 + nq * 16 + col) * 72 + ks * 32 + quad * 8];
    // wave w only overwrites rows [32w,32w+32) below = rows it alone read -> no barrier

    f32x4 O[4][2];
    float l_[2] = {0.0f, 0.0f};
#pragma unroll
    for (int nd = 0; nd < 4; ++nd)
#pragma unroll
        for (int nq = 0; nq < 2; ++nq)
#pragma unroll
            for (int r = 0; r < 4; ++r) O[nd][nq][r] = 0.0f;

    const int r8a = tid >> 3, off8 = (tid & 7) * 8;

    for (int kb = 0; kb < TTOK / 64; ++kb) {
        bf16x8 kreg[2], vreg[2];
#pragma unroll
        for (int it = 0; it < 2; ++it) {
            int r = r8a + 32 * it;
            kreg[it] = *(const bf16x8*)(Kg + base + (size_t)(kb * 64 + r) * 64 + off8);
            vreg[it] = *(const bf16x8*)(Vtg + base + (size_t)r * TTOK + kb * 64 + off8);
        }
        __syncthreads();   // prior tile's Ks/Vs reads complete
#pragma unroll
        for (int it = 0; it < 2; ++it) {
            int r = r8a + 32 * it;
            *(bf16x8*)&Ks[r * 72 + off8] = kreg[it];
            *(bf16x8*)&Vs[r * 72 + off8] = vreg[it];
        }
        __syncthreads();

        // ---- S^T = K · Q^T : s[nk][nq], rows = keys, cols = q ----
        f32x4 s[4][2];
#pragma unroll
        for (int nk = 0; nk < 4; ++nk)
#pragma unroll
            for (int nq = 0; nq < 2; ++nq)
#pragma unroll
                for (int r = 0; r < 4; ++r) s[nk][nq][r] = 0.0f;
#pragma unroll
        for (int ks = 0; ks < 2; ++ks) {
            bf16x8 kf[4];
#pragma unroll
            for (int nk = 0; nk < 4; ++nk)
                kf[nk] = *(const bf16x8*)&Ks[(nk * 16 + col) * 72 + ks * 32 + quad * 8];
#pragma unroll
            for (int nk = 0; nk < 4; ++nk)
#pragma unroll
                for (int nq = 0; nq < 2; ++nq)
                    s[nk][nq] = __builtin_amdgcn_mfma_f32_16x16x32_bf16(kf[nk], qf[nq][ks], s[nk][nq], 0, 0, 0);
        }

        // ---- p = exp2(s); accumulate per-lane l; write P^T (b64) ----
#pragma unroll
        for (int nk = 0; nk < 4; ++nk)
#pragma unroll
            for (int nq = 0; nq < 2; ++nq) {
                float p0 = exp2f(s[nk][nq][0]);
                float p1 = exp2f(s[nk][nq][1]);
                float p2 = exp2f(s[nk][nq][2]);
                float p3 = exp2f(s[nk][nq][3]);
                l_[nq] += (p0 + p1) + (p2 + p3);
                bf16x4 pk;
                pk[0] = (__bf16)p0; pk[1] = (__bf16)p1;
                pk[2] = (__bf16)p2; pk[3] = (__bf16)p3;
                *(bf16x4*)&QPs[(wave * 32 + nq * 16 + col) * 72 + nk * 16 + quad * 4] = pk;
            }

        // ---- O^T += V^T · P^T  (all intra-wave, no barrier) ----
#pragma unroll
        for (int ks = 0; ks < 2; ++ks) {
            bf16x8 pf[2];
#pragma unroll
            for (int nq = 0; nq < 2; ++nq)
                pf[nq] = *(const bf16x8*)&QPs[(wave * 32 + nq * 16 + col) * 72 + ks * 32 + quad * 8];
#pragma unroll
            for (int nd = 0; nd < 4; ++nd) {
                bf16x8 vf = *(const bf16x8*)&Vs[(nd * 16 + col) * 72 + ks * 32 + quad * 8];
#pragma unroll
                for (int nq = 0; nq < 2; ++nq)
                    O[nd][nq] = __builtin_amdgcn_mfma_f32_16x16x32_bf16(vf, pf[nq], O[nd][nq], 0, 0, 0);
            }
        }
    }

    // ---- finalize l across quads ----
#pragma unroll
    for (int nq = 0; nq < 2; ++nq) l_[nq] = qsum(l_[nq]);

    // ---- epilogue: Y = O/l ; exclusive output mod ; packed bf16 store ----
    const int b = bh >> 4, h = bh & 15;
#pragma unroll
    for (int nq = 0; nq < 2; ++nq) {
        const int q = q0 + wave * 32 + nq * 16 + col;
        const float inv = 1.0f / l_[nq];
        float y[4][4], vq[4][4];
        float yv = 0.f, v2 = 0.f, yy = 0.f;
#pragma unroll
        for (int nd = 0; nd < 4; ++nd)
#pragma unroll
            for (int r = 0; r < 4; ++r) {
                int d = nd * 16 + quad * 4 + r;
                float yval = O[nd][nq][r] * inv;
                float vval = (float)Vtg[base + (size_t)d * TTOK + q];
                y[nd][r] = yval; vq[nd][r] = vval;
                yv += yval * vval; v2 += vval * vval; yy += yval * yval;
            }
        yv = qsum(yv); v2 = qsum(v2); yy = qsum(yy);
        float scl = (v2 > 0.0f) ? yv / fmaxf(v2, 1.1754943508222875e-38f) : 0.0f;
        float zz = 0.f;
        float zv[4][4];
#pragma unroll
        for (int nd = 0; nd < 4; ++nd)
#pragma unroll
            for (int r = 0; r < 4; ++r) {
                zv[nd][r] = y[nd][r] - scl * vq[nd][r];
                zz += zv[nd][r] * zv[nd][r];
            }
        zz = qsum(zz);
        float znorm = sqrtf(zz);
        float refn  = fmaxf(sqrtf(yy), sqrtf(v2));
        bool  wipe  = (v2 > 0.0f) && (znorm <= 1.1920928955078125e-07f * 64.0f * refn);
#pragma unroll
        for (int nd = 0; nd < 4; ++nd) {
            bf16x4 pk;
#pragma unroll
            for (int r = 0; r < 4; ++r) pk[r] = (__bf16)(wipe ? 0.0f : zv[nd][r]);
            *(bf16x4*)&Zm[((size_t)(b * TTOK + q)) * DM + h * 64 + nd * 16 + quad * 4] = pk;
        }
    }
}

// =====================================================================
extern "C" void kernel_launch(void* const* d_in, const int* in_sizes, int n_in,
                              void* d_out, int out_size, void* d_ws, size_t ws_size,
                              hipStream_t stream) {
    const float* x  = (const float*)d_in[0];
    const float* Wq = (const float*)d_in[1];
    const float* Wk = (const float*)d_in[2];
    const float* Wv = (const float*)d_in[3];
    const float* Wo = (const float*)d_in[4];

    const size_t NX = (size_t)NTOK * DM;   // 4M
    const size_t NW = (size_t)DM * DM;     // 1M
    __bf16* xb  = (__bf16*)d_ws;
    __bf16* wqb = xb  + NX;
    __bf16* wkb = wqb + NW;
    __bf16* wvb = wkb + NW;
    __bf16* wob = wvb + NW;
    __bf16* Qb  = wob + NW;
    __bf16* Kb  = Qb  + NX;
    __bf16* Vtb = Kb  + NX;
    __bf16* Zmb = Vtb + NX;   // total 24M bf16 = 48 MB

    cvt_bf16<<<NX / 2048, 256, 0, stream>>>(x,  xb,  (int)NX);
    cvt_bf16<<<NW / 2048, 256, 0, stream>>>(Wq, wqb, (int)NW);
    cvt_bf16<<<NW / 2048, 256, 0, stream>>>(Wk, wkb, (int)NW);
    cvt_bf16<<<NW / 2048, 256, 0, stream>>>(Wv, wvb, (int)NW);
    cvt_bf16<<<NW / 2048, 256, 0, stream>>>(Wo, wob, (int)NW);

    gemm_bf16<0><<<dim3(DM / 128, NTOK / 128, 3), 256, 0, stream>>>(
        xb, wqb, wkb, wvb, Qb, Kb, Vtb, nullptr);

    attn_mfma<<<dim3(TTOK / 128, 32), 256, 0, stream>>>(Qb, Kb, Vtb, Zmb);

    gemm_bf16<1><<<dim3(DM / 128, NTOK / 128, 1), 256, 0, stream>>>(
        Zmb, wob, wob, wob, nullptr, nullptr, nullptr, (float*)d_out);
}

// Round 4
// 200.148 us; speedup vs baseline: 5.9874x; 1.1125x over previous
//
#include <hip/hip_runtime.h>
#include <math.h>

#define DM   1024
#define TTOK 2048
#define NTOK 4096   // B*T

typedef __bf16 bf16x8 __attribute__((ext_vector_type(8)));
typedef __bf16 bf16x4 __attribute__((ext_vector_type(4)));
typedef float  f32x4  __attribute__((ext_vector_type(4)));

// Q pre-scale: sm_scale (1/8) * log2(e)  -> allows p = exp2(s)
#define QSCALE 0.18033688011112042f

#if defined(__has_builtin)
#if __has_builtin(__builtin_amdgcn_exp2f)
#define EXP2F(x) __builtin_amdgcn_exp2f(x)
#endif
#endif
#ifndef EXP2F
#define EXP2F(x) exp2f(x)
#endif

#define GLDS16(g, l) __builtin_amdgcn_global_load_lds( \
    (__attribute__((address_space(1))) void*)(g),      \
    (__attribute__((address_space(3))) void*)(l), 16, 0, 0)

// sum across the 4 quads (lanes ^16, ^32)
__device__ __forceinline__ float qsum(float v) {
    v += __shfl_xor(v, 16, 64);
    v += __shfl_xor(v, 32, 64);
    return v;
}

// ---------------- fp32 -> bf16 convert: x + 4 weights in ONE launch ----------------
// layout: [x: 4M][Wq: 1M][Wk: 1M][Wv: 1M][Wo: 1M] -> same order in dst
__global__ __launch_bounds__(256)
void cvt_all(const float* __restrict__ x,  const float* __restrict__ Wq,
             const float* __restrict__ Wk, const float* __restrict__ Wv,
             const float* __restrict__ Wo, __bf16* __restrict__ dst) {
    size_t g = ((size_t)blockIdx.x * 256 + threadIdx.x) * 8;
    const float* s;
    size_t off;
    const size_t NX = (size_t)NTOK * DM;   // 4M
    if (g < NX) { s = x; off = g; }
    else {
        size_t gg = g - NX;
        int w = (int)(gg >> 20);           // 1M-element segments
        off = gg & ((1u << 20) - 1);
        s = (w == 0) ? Wq : (w == 1) ? Wk : (w == 2) ? Wv : Wo;
        off += 0;  // segment-local
    }
    float4 a = *(const float4*)(s + off);
    float4 b = *(const float4*)(s + off + 4);
    bf16x8 v;
    v[0] = (__bf16)a.x; v[1] = (__bf16)a.y; v[2] = (__bf16)a.z; v[3] = (__bf16)a.w;
    v[4] = (__bf16)b.x; v[5] = (__bf16)b.y; v[6] = (__bf16)b.z; v[7] = (__bf16)b.w;
    *(bf16x8*)(dst + g) = v;
}

// =====================================================================
// bf16 MFMA GEMM: C[m,n] = sum_k A[m,k] * W[n,k]
// MODE 0: z=0 -> Q[b,h,t,d] scaled by QSCALE; z=1 -> K[b,h,t,d];
//         z=2 -> Vt[b,h,d,t] (packed b64 stores along t)
// MODE 1: fp32 row-major output (out-projection)
// =====================================================================
template<int MODE>
__global__ __launch_bounds__(256)
void gemm_bf16(const __bf16* __restrict__ A,
               const __bf16* __restrict__ W0, const __bf16* __restrict__ W1,
               const __bf16* __restrict__ W2,
               __bf16* __restrict__ Oq, __bf16* __restrict__ Ok,
               __bf16* __restrict__ Ovt, float* __restrict__ Of)
{
    const int z = (MODE == 0) ? blockIdx.z : 0;
    const __bf16* W = (z == 0) ? W0 : (z == 1) ? W1 : W2;

    __shared__ __attribute__((aligned(16))) __bf16 As[128 * 32];
    __shared__ __attribute__((aligned(16))) __bf16 Bs[128 * 32];

    const int tid  = threadIdx.x;
    const int lane = tid & 63;
    const int wave = tid >> 6;
    const int wm = wave & 1, wn = wave >> 1;
    const int col = lane & 15, quad = lane >> 4;
    const int m0 = blockIdx.y * 128, n0 = blockIdx.x * 128;

    const __bf16* Ag = A + (size_t)(m0 + (tid >> 2)) * DM + (tid & 3) * 8;
    const __bf16* Wg = W + (size_t)(n0 + (tid >> 2)) * DM + (tid & 3) * 8;
    __bf16* lA = As + tid * 8;
    __bf16* lB = Bs + tid * 8;

    f32x4 acc[4][4];
#pragma unroll
    for (int i = 0; i < 4; ++i)
#pragma unroll
        for (int j = 0; j < 4; ++j)
#pragma unroll
            for (int r = 0; r < 4; ++r) acc[i][j][r] = 0.0f;

    for (int k0 = 0; k0 < DM; k0 += 32) {
        __syncthreads();
        GLDS16(Ag + k0,                   lA);
        GLDS16(Ag + (size_t)64 * DM + k0, lA + 2048);
        GLDS16(Wg + k0,                   lB);
        GLDS16(Wg + (size_t)64 * DM + k0, lB + 2048);
        __syncthreads();
        bf16x8 af[4], bfr[4];
#pragma unroll
        for (int i = 0; i < 4; ++i)
            af[i] = *(const bf16x8*)&As[(wm * 64 + i * 16 + col) * 32 + quad * 8];
#pragma unroll
        for (int j = 0; j < 4; ++j)
            bfr[j] = *(const bf16x8*)&Bs[(wn * 64 + j * 16 + col) * 32 + quad * 8];
#pragma unroll
        for (int i = 0; i < 4; ++i)
#pragma unroll
            for (int j = 0; j < 4; ++j)
                acc[i][j] = __builtin_amdgcn_mfma_f32_16x16x32_bf16(af[i], bfr[j], acc[i][j], 0, 0, 0);
    }

#pragma unroll
    for (int i = 0; i < 4; ++i) {
#pragma unroll
        for (int j = 0; j < 4; ++j) {
            const int mb = m0 + wm * 64 + i * 16 + quad * 4;   // multiple of 4
            const int n  = n0 + wn * 64 + j * 16 + col;
            if (MODE == 1) {
#pragma unroll
                for (int r = 0; r < 4; ++r)
                    Of[(size_t)(mb + r) * DM + n] = acc[i][j][r];
            } else {
                const int b = mb >> 11, t = mb & 2047;
                const int h = n >> 6,  d = n & 63;
                if (z == 2) {
                    bf16x4 pk;
#pragma unroll
                    for (int r = 0; r < 4; ++r) pk[r] = (__bf16)acc[i][j][r];
                    *(bf16x4*)&Ovt[(((size_t)(b * 16 + h)) * 64 + d) * TTOK + t] = pk;
                } else {
                    __bf16* dst = ((z == 0) ? Oq : Ok) +
                                  ((((size_t)(b * 16 + h)) * TTOK + t) * 64 + d);
                    const float sc = (z == 0) ? QSCALE : 1.0f;
#pragma unroll
                    for (int r = 0; r < 4; ++r) dst[(size_t)r * 64] = (__bf16)(acc[i][j][r] * sc);
                }
            }
        }
    }
}

// =====================================================================
// MFMA flash attention v3: 512 threads (8 waves), 128 q/block, 16 q/wave.
// S^T = K·Q^T ; p = exp2 (raw v_exp_f32, log2e folded into Q);
// l accumulated on the MATRIX pipe via l = mfma(ones, P, l);
// O^T = V^T·P ; exclusive-mod epilogue.
// LDS 36 KB: Ks/Vs 9K + QPs 18K (Q stage -> P[q][key], intra-wave rows).
// =====================================================================
__global__ __launch_bounds__(512)
void attn_mfma(const __bf16* __restrict__ Qg, const __bf16* __restrict__ Kg,
               const __bf16* __restrict__ Vtg, __bf16* __restrict__ Zm)
{
    const int bh = blockIdx.y;
    const int q0 = blockIdx.x * 128;
    const size_t base = (size_t)bh * TTOK * 64;

    __shared__ __attribute__((aligned(16))) __bf16 Ks[64 * 72];
    __shared__ __attribute__((aligned(16))) __bf16 Vs[64 * 72];     // [d][key]
    __shared__ __attribute__((aligned(16))) __bf16 QPs[128 * 72];   // Q stage -> P [q][key]

    const int tid  = threadIdx.x;
    const int lane = tid & 63, wave = tid >> 6;   // wave 0..7
    const int col  = lane & 15, quad = lane >> 4;

    // ---- stage Q (pre-scaled by QSCALE in GEMM) ----
#pragma unroll
    for (int it = 0; it < 2; ++it) {
        int c = tid + 512 * it;
        int r = c >> 3, off = (c & 7) * 8;
        *(bf16x8*)&QPs[r * 72 + off] =
            *(const bf16x8*)(Qg + base + (size_t)(q0 + r) * 64 + off);
    }
    __syncthreads();
    bf16x8 qf[2];
#pragma unroll
    for (int ks = 0; ks < 2; ++ks)
        qf[ks] = *(const bf16x8*)&QPs[(wave * 16 + col) * 72 + ks * 32 + quad * 8];
    // wave w only overwrites rows [16w,16w+16) below = rows only it read -> no barrier

    bf16x8 ones;
#pragma unroll
    for (int i = 0; i < 8; ++i) ones[i] = (__bf16)1.0f;

    f32x4 O[4], lacc;
#pragma unroll
    for (int r = 0; r < 4; ++r) {
        lacc[r] = 0.0f;
#pragma unroll
        for (int nd = 0; nd < 4; ++nd) O[nd][r] = 0.0f;
    }

    const int rs = tid >> 3, offs = (tid & 7) * 8;   // 64 rows x 128 B staging

    for (int kb = 0; kb < TTOK / 64; ++kb) {
        bf16x8 kreg = *(const bf16x8*)(Kg + base + (size_t)(kb * 64 + rs) * 64 + offs);
        bf16x8 vreg = *(const bf16x8*)(Vtg + base + (size_t)rs * TTOK + kb * 64 + offs);
        __syncthreads();   // prior tile's Ks/Vs frag reads complete
        *(bf16x8*)&Ks[rs * 72 + offs] = kreg;
        *(bf16x8*)&Vs[rs * 72 + offs] = vreg;
        __syncthreads();

        // ---- S^T = K · Q^T : rows = keys, cols = q(16) ----
        f32x4 s[4];
#pragma unroll
        for (int nk = 0; nk < 4; ++nk)
#pragma unroll
            for (int r = 0; r < 4; ++r) s[nk][r] = 0.0f;
#pragma unroll
        for (int ks = 0; ks < 2; ++ks) {
            bf16x8 kf[4];
#pragma unroll
            for (int nk = 0; nk < 4; ++nk)
                kf[nk] = *(const bf16x8*)&Ks[(nk * 16 + col) * 72 + ks * 32 + quad * 8];
#pragma unroll
            for (int nk = 0; nk < 4; ++nk)
                s[nk] = __builtin_amdgcn_mfma_f32_16x16x32_bf16(kf[nk], qf[ks], s[nk], 0, 0, 0);
        }

        // ---- p = exp2(s) (raw v_exp_f32); write P[q][key] (b64) ----
#pragma unroll
        for (int nk = 0; nk < 4; ++nk) {
            float p0 = EXP2F(s[nk][0]);
            float p1 = EXP2F(s[nk][1]);
            float p2 = EXP2F(s[nk][2]);
            float p3 = EXP2F(s[nk][3]);
            bf16x4 pk;
            pk[0] = (__bf16)p0; pk[1] = (__bf16)p1;
            pk[2] = (__bf16)p2; pk[3] = (__bf16)p3;
            *(bf16x4*)&QPs[(wave * 16 + col) * 72 + nk * 16 + quad * 4] = pk;
        }

        // ---- O^T += V^T · P ; l += 1 · P  (all intra-wave) ----
#pragma unroll
        for (int ks = 0; ks < 2; ++ks) {
            bf16x8 pf = *(const bf16x8*)&QPs[(wave * 16 + col) * 72 + ks * 32 + quad * 8];
            lacc = __builtin_amdgcn_mfma_f32_16x16x32_bf16(ones, pf, lacc, 0, 0, 0);
#pragma unroll
            for (int nd = 0; nd < 4; ++nd) {
                bf16x8 vf = *(const bf16x8*)&Vs[(nd * 16 + col) * 72 + ks * 32 + quad * 8];
                O[nd] = __builtin_amdgcn_mfma_f32_16x16x32_bf16(vf, pf, O[nd], 0, 0, 0);
            }
        }
    }

    // every lane holds l[q=col] in each lacc component (all rows of 1-matrix identical)
    const float inv = 1.0f / lacc[0];

    // ---- epilogue: Y = O/l ; exclusive output mod ; packed bf16 store ----
    const int b = bh >> 4, h = bh & 15;
    const int q = q0 + wave * 16 + col;
    float y[4][4], vq[4][4];
    float yv = 0.f, v2 = 0.f, yy = 0.f;
#pragma unroll
    for (int nd = 0; nd < 4; ++nd)
#pragma unroll
        for (int r = 0; r < 4; ++r) {
            int d = nd * 16 + quad * 4 + r;
            float yval = O[nd][r] * inv;
            float vval = (float)Vtg[base + (size_t)d * TTOK + q];
            y[nd][r] = yval; vq[nd][r] = vval;
            yv += yval * vval; v2 += vval * vval; yy += yval * yval;
        }
    yv = qsum(yv); v2 = qsum(v2); yy = qsum(yy);
    float scl = (v2 > 0.0f) ? yv / fmaxf(v2, 1.1754943508222875e-38f) : 0.0f;
    float zz = 0.f;
    float zv[4][4];
#pragma unroll
    for (int nd = 0; nd < 4; ++nd)
#pragma unroll
        for (int r = 0; r < 4; ++r) {
            zv[nd][r] = y[nd][r] - scl * vq[nd][r];
            zz += zv[nd][r] * zv[nd][r];
        }
    zz = qsum(zz);
    float znorm = sqrtf(zz);
    float refn  = fmaxf(sqrtf(yy), sqrtf(v2));
    bool  wipe  = (v2 > 0.0f) && (znorm <= 1.1920928955078125e-07f * 64.0f * refn);
#pragma unroll
    for (int nd = 0; nd < 4; ++nd) {
        bf16x4 pk;
#pragma unroll
        for (int r = 0; r < 4; ++r) pk[r] = (__bf16)(wipe ? 0.0f : zv[nd][r]);
        *(bf16x4*)&Zm[((size_t)(b * TTOK + q)) * DM + h * 64 + nd * 16 + quad * 4] = pk;
    }
}

// =====================================================================
extern "C" void kernel_launch(void* const* d_in, const int* in_sizes, int n_in,
                              void* d_out, int out_size, void* d_ws, size_t ws_size,
                              hipStream_t stream) {
    const float* x  = (const float*)d_in[0];
    const float* Wq = (const float*)d_in[1];
    const float* Wk = (const float*)d_in[2];
    const float* Wv = (const float*)d_in[3];
    const float* Wo = (const float*)d_in[4];

    const size_t NX = (size_t)NTOK * DM;   // 4M
    const size_t NW = (size_t)DM * DM;     // 1M
    __bf16* xb  = (__bf16*)d_ws;
    __bf16* wqb = xb  + NX;
    __bf16* wkb = wqb + NW;
    __bf16* wvb = wkb + NW;
    __bf16* wob = wvb + NW;
    __bf16* Qb  = wob + NW;
    __bf16* Kb  = Qb  + NX;
    __bf16* Vtb = Kb  + NX;
    __bf16* Zmb = Vtb + NX;   // total 24M bf16 = 48 MB

    // single fused convert launch: (4M + 4*1M) / (256*8) = 4096 blocks
    cvt_all<<<(NX + 4 * NW) / 2048, 256, 0, stream>>>(x, Wq, Wk, Wv, Wo, xb);

    gemm_bf16<0><<<dim3(DM / 128, NTOK / 128, 3), 256, 0, stream>>>(
        xb, wqb, wkb, wvb, Qb, Kb, Vtb, nullptr);

    attn_mfma<<<dim3(TTOK / 128, 32), 512, 0, stream>>>(Qb, Kb, Vtb, Zmb);

    gemm_bf16<1><<<dim3(DM / 128, NTOK / 128, 1), 256, 0, stream>>>(
        Zmb, wob, wob, wob, nullptr, nullptr, nullptr, (float*)d_out);
}